// Round 8
// baseline (195.162 us; speedup 1.0000x reference)
//
#include <hip/hip_runtime.h>
#include <hip/hip_bf16.h>
#include <stdint.h>

#define IN_F   4096
#define OUT_F  4096
#define M_ROWS 2048
#define NG     32
#define GRP    128

typedef int   v4i  __attribute__((ext_vector_type(4)));
typedef float f32x4 __attribute__((ext_vector_type(4)));

typedef const void __attribute__((address_space(1))) cv_g;
typedef void       __attribute__((address_space(3))) v_l;

__device__ __forceinline__ void async16(const void* g, void* l) {
  // global -> LDS DMA, 16B/lane; LDS dest = wave-uniform base + lane*16.
  __builtin_amdgcn_global_load_lds((cv_g*)g, (v_l*)l, 16, 0, 0);
}

// perm dtype flag (fallback path only): 1 if int64, 0 if int32.
__device__ int g_perm_is64;

__global__ void decode_flag(const void* __restrict__ perm_raw) {
  if (threadIdx.x == 0 && blockIdx.x == 0) {
    const int* w = (const int*)perm_raw;
    int ok = 1;
    for (int j = 0; j < 32; ++j) {
      int lo = w[2 * j], hi = w[2 * j + 1];
      if (hi != 0 || lo < 0 || lo >= IN_F) { ok = 0; break; }
    }
    g_perm_is64 = ok;
  }
}

// Fused preprocessing (int8 edition) -- unchanged from verified version.
__global__ __launch_bounds__(256) void prep(const float* __restrict__ x,
                                            const int* __restrict__ w_q,
                                            const void* __restrict__ perm_raw,
                                            char* __restrict__ xq,
                                            char* __restrict__ w8,
                                            float* __restrict__ sxr) {
  __shared__ float sx[IN_F];
  __shared__ float red[4];
  __shared__ int sflag;
  const int b = blockIdx.x;
  const int t = threadIdx.x;

  if (b < M_ROWS) {
    const int m = b;
    const float* xr = x + (size_t)m * IN_F;
#pragma unroll
    for (int u = 0; u < 4; ++u) {
      int idx = (u * 256 + t) * 4;
      *(float4*)&sx[idx] = *(const float4*)&xr[idx];
    }
    if (t < 64) {
      const int* w = (const int*)perm_raw;
      int j = t & 31;
      int lo = w[2 * j], hi = w[2 * j + 1];
      int cond = (hi == 0 && lo >= 0 && lo < IN_F);
      unsigned long long bal = __ballot(cond);
      if (t == 0) sflag = (bal == ~0ull) ? 1 : 0;
    }
    __syncthreads();
    const int f = sflag;
    const long long* p64 = (const long long*)perm_raw;
    const int*       p32 = (const int*)perm_raw;
    const int jb = t * 16;
    float vals[16];
    float lmax = 0.f;
#pragma unroll
    for (int u = 0; u < 16; ++u) {
      int pj = f ? (int)p64[jb + u] : p32[jb + u];
      float v = sx[pj];
      vals[u] = v;
      lmax = fmaxf(lmax, fabsf(v));
    }
#pragma unroll
    for (int d = 1; d < 64; d <<= 1)
      lmax = fmaxf(lmax, __shfl_xor(lmax, d, 64));
    if ((t & 63) == 0) red[t >> 6] = lmax;
    __syncthreads();
    float rmax = fmaxf(fmaxf(red[0], red[1]), fmaxf(red[2], red[3]));
    float inv = (rmax > 0.f) ? 127.f / rmax : 0.f;
    if (t == 0) sxr[m] = rmax / 127.f;
    char q[16] __attribute__((aligned(16)));
#pragma unroll
    for (int u = 0; u < 16; ++u)
      q[u] = (char)__float2int_rn(vals[u] * inv);
    *(uint4*)(xq + (size_t)m * IN_F + jb) = *(const uint4*)q;
  } else {
    const int o  = b - M_ROWS;
    const int kb = t * 16;
    const int* wr = w_q + (size_t)o * IN_F + kb;
    int4 w0 = *(const int4*)(wr + 0);
    int4 w1 = *(const int4*)(wr + 4);
    int4 w2 = *(const int4*)(wr + 8);
    int4 w3 = *(const int4*)(wr + 12);
    char q[16] __attribute__((aligned(16)));
    q[0]=(char)w0.x; q[1]=(char)w0.y; q[2]=(char)w0.z; q[3]=(char)w0.w;
    q[4]=(char)w1.x; q[5]=(char)w1.y; q[6]=(char)w1.z; q[7]=(char)w1.w;
    q[8]=(char)w2.x; q[9]=(char)w2.y; q[10]=(char)w2.z; q[11]=(char)w2.w;
    q[12]=(char)w3.x; q[13]=(char)w3.y; q[14]=(char)w3.z; q[15]=(char)w3.w;
    *(uint4*)(w8 + (size_t)o * IN_F + kb) = *(const uint4*)q;
  }
}

// C[m,o] = sxr[m] * sum_g s_w[g,o] * (int8 dot over group g) + bias[o]
//
// R16: occupancy doubling on the verified shell. Per-pipe accounting at the
// 55us plateau (per SIMD, 132Kcyc): MFMA 42K (32%), VALU 43K (33%), LDS
// 49-65K (~40%) -- no pipe saturated, total ~= SUM of pipes => phases are
// serialized. Cause: 2 waves/SIMD in barrier lockstep (Occupancy 17%) --
// nobody fills any wave's stall. Fix (Guideline 1): same 128x128 tile, same
// BK=128 double-buffer, same 72KB LDS, same 2 blocks/CU -- but 512 threads:
// 8 waves of 32x64 (4M x 2N) => 16 waves/CU = 4 waves/SIMD.
// The 32x64 wave tile is the unique choice fitting 4 waves/SIMD: accf 32 +
// transient acci 32 + frags/addr ~50 => ~116 VGPR <= 128 cap (64x64 needs
// accf+acci=128 alone -- why R9's 8x64x64 couldn't help). Cost accepted:
// per-CU LDS fragment reads +50% (B panels read by 4 row-waves) ~= 65Kcyc,
// still below the 132K being paid. Staging XOR geometry + counted-vmcnt
// barriers (R15) carried over; 2048 chunks / 512 thr = 4 DMAs/thread ->
// vmcnt(4). Sentinels: VGPR<=128, Occupancy ~2x, WRITE ~33MB.
__global__ __launch_bounds__(512, 4) void gemm_i8(
    const char* __restrict__ A,     // xq  M x K int8
    const char* __restrict__ B,     // w8  N x K int8
    const float* __restrict__ s_w,  // NG x OUT_F
    const float* __restrict__ sxr,  // M
    const float* __restrict__ bias,
    float* __restrict__ C) {
  __shared__ char smem[2][32768];           // per buf: A 16384 | B 16384 bytes
  __shared__ unsigned short sws[NG * 128];  // s_w for this block's 128 cols, bf16

  const int tid  = threadIdx.x;
  const int wave = tid >> 6;
  const int lane = tid & 63;
  const int bm = blockIdx.y << 7;
  const int bn = blockIdx.x << 7;
  const int wm = (wave >> 1) << 5;   // 4 wave-rows of 32
  const int wn = (wave & 1) << 6;    // 2 wave-cols of 64
  const int lrow = lane & 15;
  const int quad = lane >> 4;

  // stage s_w block into LDS as bf16 (keeps the K-loop free of global loads)
#pragma unroll
  for (int u = 0; u < 8; ++u) {
    int idx = u * 512 + tid;               // [g][c], c = local col
    int g = idx >> 7, c = idx & 127;
    __hip_bfloat16 h = __float2bfloat16(s_w[(size_t)g * OUT_F + bn + c]);
    sws[idx] = *(unsigned short*)&h;
  }

  f32x4 accf[2][4] = {};

  // Staging: per buf 2048 chunks of 16B. Round r = h*8+wave (h=0..3) covers
  // chunks c = r*64 + lane. c<1024 -> A (row=c>>3), else B. kc = (c&7)^(row&7).
  // Each 512-chunk round lies entirely in A (h=0,1) or B (h=2,3).
  const char* gp[4];
  int lofs[4];
#pragma unroll
  for (int h = 0; h < 4; ++h) {
    int c0 = (h * 8 + wave) * 64;
    int c  = c0 + lane;
    if (c < 1024) {
      int row = c >> 3;
      int kc  = (c & 7) ^ (row & 7);
      gp[h]   = A + (size_t)(bm + row) * IN_F + kc * 16;
      lofs[h] = c0 * 16;
    } else {
      int cb  = c - 1024;
      int row = cb >> 3;
      int kc  = (cb & 7) ^ (row & 7);
      gp[h]   = B + (size_t)(bn + row) * IN_F + kc * 16;
      lofs[h] = 16384 + (c0 - 1024) * 16;
    }
  }

  auto stage = [&](int p, int kn) {
#pragma unroll
    for (int h = 0; h < 4; ++h)
      async16(gp[h] + kn, &smem[p][lofs[h]]);
  };

  auto compute = [&](int p, int g) {
    const char* bufA = smem[p];
    const char* bufB = smem[p] + 16384;
    v4i acci[2][4] = {};
#pragma unroll
    for (int s = 0; s < 2; ++s) {
      v4i af[2], bf[4];
#pragma unroll
      for (int i = 0; i < 2; ++i) {
        int row = wm + i * 16 + lrow;
        af[i] = *(const v4i*)&bufA[row * 128 + (((s << 2) + quad) ^ (row & 7)) * 16];
      }
#pragma unroll
      for (int j = 0; j < 4; ++j) {
        int row = wn + j * 16 + lrow;
        bf[j] = *(const v4i*)&bufB[row * 128 + (((s << 2) + quad) ^ (row & 7)) * 16];
      }
#pragma unroll
      for (int i = 0; i < 2; ++i)
#pragma unroll
        for (int j = 0; j < 4; ++j)
          acci[i][j] = __builtin_amdgcn_mfma_i32_16x16x64_i8(af[i], bf[j], acci[i][j], 0, 0, 0);
    }
    // per-group rescale (exact int32 -> f32, scaled by s_w[g, col])
    float swv[4];
#pragma unroll
    for (int j = 0; j < 4; ++j) {
      unsigned int u = sws[g * 128 + wn + j * 16 + lrow];
      swv[j] = __uint_as_float(u << 16);
    }
#pragma unroll
    for (int i = 0; i < 2; ++i)
#pragma unroll
      for (int j = 0; j < 4; ++j)
#pragma unroll
        for (int r = 0; r < 4; ++r)
          accf[i][j][r] += swv[j] * (float)acci[i][j][r];
  };

  // prologue: stage tiles 0 and 1 (4 DMAs each; queue = 8). vmcnt(4)
  // retires exactly tile 0's DMAs; tile 1's stay in flight across the
  // barrier with a full compute phase to land. lgkmcnt(0) publishes sws.
  stage(0, 0);
  stage(1, 128);
  asm volatile("s_waitcnt vmcnt(4) lgkmcnt(0)" ::: "memory");
  __builtin_amdgcn_s_barrier();
  asm volatile("" ::: "memory");

  for (int k0 = 0; k0 < IN_F; k0 += 256) {
    compute(0, k0 >> 7);                       // read buf0 (tile e)
    asm volatile("s_waitcnt lgkmcnt(0)" ::: "memory");
    __builtin_amdgcn_s_barrier();              // WAR: all waves done with buf0
    asm volatile("" ::: "memory");
    if (k0 + 256 < IN_F) {
      stage(0, k0 + 256);                      // tile e+2 -> buf0
      asm volatile("s_waitcnt vmcnt(4)" ::: "memory");  // retire tile e+1 DMAs
    } else {
      asm volatile("s_waitcnt vmcnt(0)" ::: "memory");  // tail: drain tile 31
    }
    __builtin_amdgcn_s_barrier();              // publish buf1
    asm volatile("" ::: "memory");
    compute(1, (k0 >> 7) + 1);                 // read buf1 (tile e+1)
    if (k0 + 256 < IN_F) {
      asm volatile("s_waitcnt lgkmcnt(0)" ::: "memory");
      __builtin_amdgcn_s_barrier();            // WAR: all waves done with buf1
      asm volatile("" ::: "memory");
      stage(1, k0 + 384);                      // tile e+3 -> buf1
      asm volatile("s_waitcnt vmcnt(4)" ::: "memory");  // retire tile e+2 DMAs
      __builtin_amdgcn_s_barrier();            // publish buf0
      asm volatile("" ::: "memory");
    }
  }

  // Epilogue: C/D layout col=lane&15, row=quad*4+reg (dtype-independent,
  // m89/m121-128). Apply per-row x-scale + bias.
#pragma unroll
  for (int i = 0; i < 2; ++i) {
    int r0 = bm + wm + i * 16 + quad * 4;
    float sxv[4];
#pragma unroll
    for (int r = 0; r < 4; ++r) sxv[r] = sxr[r0 + r];  // quad-broadcast loads
#pragma unroll
    for (int j = 0; j < 4; ++j) {
      int col = bn + wn + j * 16 + lrow;
      float bv = bias[col];
#pragma unroll
      for (int r = 0; r < 4; ++r)
        C[(size_t)(r0 + r) * OUT_F + col] = sxv[r] * accf[i][j][r] + bv;
    }
  }
}

// Correct-but-slow fp32 fallback if workspace is too small.
__global__ void naive_fallback(const float* __restrict__ x, const int* __restrict__ w_q,
                               const float* __restrict__ s_w, const void* __restrict__ perm_raw,
                               const float* __restrict__ bias, float* __restrict__ out) {
  int t = blockIdx.x * blockDim.x + threadIdx.x;
  int m = t >> 12;
  int o = t & 4095;
  const int f = g_perm_is64;
  const long long* p64 = (const long long*)perm_raw;
  const int*       p32 = (const int*)perm_raw;
  const float* xr = x + (size_t)m * IN_F;
  const int*   wr = w_q + (size_t)o * IN_F;
  float acc = 0.f;
  for (int g = 0; g < NG; ++g) {
    float part = 0.f;
    for (int k = 0; k < GRP; ++k) {
      int j = g * GRP + k;
      int pj = f ? (int)p64[j] : p32[j];
      part += xr[pj] * (float)wr[j];
    }
    acc += part * s_w[(size_t)g * OUT_F + o];
  }
  out[t] = acc + bias[o];
}

extern "C" void kernel_launch(void* const* d_in, const int* in_sizes, int n_in,
                              void* d_out, int out_size, void* d_ws, size_t ws_size,
                              hipStream_t stream) {
  const float* x    = (const float*)d_in[0];
  const int*   w_q  = (const int*)d_in[1];
  const float* s_w  = (const float*)d_in[2];
  const void*  perm = d_in[3];   // int64 or int32 -- detected on device
  const float* bias = (const float*)d_in[4];
  float* out = (float*)d_out;

  const size_t xq_bytes = (size_t)M_ROWS * IN_F;            // 8 MiB int8
  const size_t w8_bytes = (size_t)OUT_F * IN_F;             // 16 MiB int8
  const size_t sx_bytes = (size_t)M_ROWS * sizeof(float);   // 8 KiB
  const size_t need = xq_bytes + w8_bytes + sx_bytes;

  if (ws_size < need) {
    decode_flag<<<1, 64, 0, stream>>>(perm);
    naive_fallback<<<(M_ROWS * OUT_F) / 256, 256, 0, stream>>>(x, w_q, s_w, perm, bias, out);
    return;
  }

  char*  xq  = (char*)d_ws;
  char*  w8  = (char*)d_ws + xq_bytes;
  float* sxr = (float*)((char*)d_ws + xq_bytes + w8_bytes);

  prep<<<M_ROWS + OUT_F, 256, 0, stream>>>(x, w_q, perm, xq, w8, sxr);

  dim3 grid(OUT_F / 128, M_ROWS / 128);  // 32 x 16 = 512 blocks, 2/CU
  gemm_i8<<<grid, 512, 0, stream>>>(xq, w8, s_w, sxr, bias, out);
}

// Round 9
// 182.980 us; speedup vs baseline: 1.0666x; 1.0666x over previous
//
#include <hip/hip_runtime.h>
#include <hip/hip_bf16.h>
#include <stdint.h>

#define IN_F   4096
#define OUT_F  4096
#define M_ROWS 2048
#define NG     32
#define GRP    128

typedef int   v4i  __attribute__((ext_vector_type(4)));
typedef float f32x4 __attribute__((ext_vector_type(4)));

typedef const void __attribute__((address_space(1))) cv_g;
typedef void       __attribute__((address_space(3))) v_l;

__device__ __forceinline__ void async16(const void* g, void* l) {
  // global -> LDS DMA, 16B/lane; LDS dest = wave-uniform base + lane*16.
  __builtin_amdgcn_global_load_lds((cv_g*)g, (v_l*)l, 16, 0, 0);
}

// perm dtype flag (fallback path only): 1 if int64, 0 if int32.
__device__ int g_perm_is64;

__global__ void decode_flag(const void* __restrict__ perm_raw) {
  if (threadIdx.x == 0 && blockIdx.x == 0) {
    const int* w = (const int*)perm_raw;
    int ok = 1;
    for (int j = 0; j < 32; ++j) {
      int lo = w[2 * j], hi = w[2 * j + 1];
      if (hi != 0 || lo < 0 || lo >= IN_F) { ok = 0; break; }
    }
    g_perm_is64 = ok;
  }
}

// Fused preprocessing, R17 edition. Change vs verified prep: the x-path no
// longer re-reads the 32KB perm array from global with 128B-stride scalar
// loads (64 cache lines PER WAVE INSTRUCTION, ~8.4M line-requests + ~64MB
// of L2 traffic across the 2048 row-blocks). Instead each block stages perm
// ONCE, coalesced (int4 loads), into an 8KB ushort LDS table and gathers
// indices from LDS. Values < 4096 always fit ushort. w-path unchanged.
__global__ __launch_bounds__(256) void prep(const float* __restrict__ x,
                                            const int* __restrict__ w_q,
                                            const void* __restrict__ perm_raw,
                                            char* __restrict__ xq,
                                            char* __restrict__ w8,
                                            float* __restrict__ sxr) {
  __shared__ float sx[IN_F];               // 16 KB
  __shared__ unsigned short sperm[IN_F];   // 8 KB
  __shared__ float red[4];
  __shared__ int sflag;
  const int b = blockIdx.x;
  const int t = threadIdx.x;

  if (b < M_ROWS) {
    const int m = b;
    const float* xr = x + (size_t)m * IN_F;
    // phase 0: stage x row (coalesced float4) + detect perm dtype
#pragma unroll
    for (int u = 0; u < 4; ++u) {
      int idx = (u * 256 + t) * 4;
      *(float4*)&sx[idx] = *(const float4*)&xr[idx];
    }
    if (t < 64) {
      const int* w = (const int*)perm_raw;
      int j = t & 31;  // lanes 32..63 duplicate 0..31 -> same ballot bits
      int lo = w[2 * j], hi = w[2 * j + 1];
      // int64 LE values in [0,4096): hi word always 0. int32 perm: w[2j+1]
      // is a perm value, ==0 for at most one j -> ballot never all-ones.
      int cond = (hi == 0 && lo >= 0 && lo < IN_F);
      unsigned long long bal = __ballot(cond);
      if (t == 0) sflag = (bal == ~0ull) ? 1 : 0;
    }
    __syncthreads();
    // phase 1: stage perm coalesced -> ushort LDS table
    if (sflag) {
      const int4* p4 = (const int4*)perm_raw;  // 16B = 2 int64 (lo at .x/.z)
#pragma unroll
      for (int u = 0; u < 8; ++u) {
        int idx = u * 256 + t;
        int4 v = p4[idx];
        sperm[2 * idx]     = (unsigned short)v.x;
        sperm[2 * idx + 1] = (unsigned short)v.z;
      }
    } else {
      const int4* p4 = (const int4*)perm_raw;  // 16B = 4 int32
#pragma unroll
      for (int u = 0; u < 4; ++u) {
        int idx = u * 256 + t;
        int4 v = p4[idx];
        sperm[4 * idx]     = (unsigned short)v.x;
        sperm[4 * idx + 1] = (unsigned short)v.y;
        sperm[4 * idx + 2] = (unsigned short)v.z;
        sperm[4 * idx + 3] = (unsigned short)v.w;
      }
    }
    __syncthreads();
    // phase 2: gather + row-max + quantize
    const int jb = t * 16;
    float vals[16];
    float lmax = 0.f;
#pragma unroll
    for (int u = 0; u < 16; ++u) {
      int pj = sperm[jb + u];
      float v = sx[pj];
      vals[u] = v;
      lmax = fmaxf(lmax, fabsf(v));
    }
#pragma unroll
    for (int d = 1; d < 64; d <<= 1)
      lmax = fmaxf(lmax, __shfl_xor(lmax, d, 64));
    if ((t & 63) == 0) red[t >> 6] = lmax;
    __syncthreads();
    float rmax = fmaxf(fmaxf(red[0], red[1]), fmaxf(red[2], red[3]));
    float inv = (rmax > 0.f) ? 127.f / rmax : 0.f;
    if (t == 0) sxr[m] = rmax / 127.f;
    char q[16] __attribute__((aligned(16)));
#pragma unroll
    for (int u = 0; u < 16; ++u)
      q[u] = (char)__float2int_rn(vals[u] * inv);
    *(uint4*)(xq + (size_t)m * IN_F + jb) = *(const uint4*)q;
  } else {
    // pack weights: one block per output row o; thread t -> 16 consecutive k
    const int o  = b - M_ROWS;
    const int kb = t * 16;
    const int* wr = w_q + (size_t)o * IN_F + kb;
    int4 w0 = *(const int4*)(wr + 0);
    int4 w1 = *(const int4*)(wr + 4);
    int4 w2 = *(const int4*)(wr + 8);
    int4 w3 = *(const int4*)(wr + 12);
    char q[16] __attribute__((aligned(16)));
    q[0]=(char)w0.x; q[1]=(char)w0.y; q[2]=(char)w0.z; q[3]=(char)w0.w;
    q[4]=(char)w1.x; q[5]=(char)w1.y; q[6]=(char)w1.z; q[7]=(char)w1.w;
    q[8]=(char)w2.x; q[9]=(char)w2.y; q[10]=(char)w2.z; q[11]=(char)w2.w;
    q[12]=(char)w3.x; q[13]=(char)w3.y; q[14]=(char)w3.z; q[15]=(char)w3.w;
    *(uint4*)(w8 + (size_t)o * IN_F + kb) = *(const uint4*)q;
  }
}

// C[m,o] = sxr[m] * sum_g s_w[g,o] * (int8 dot over group g) + bias[o]
//
// R17 gemm = R16 VERBATIM (control; best-equal at 55.5us, 64 VGPR, 32%
// occupancy, no spill). 128x128 tile, BK=128 dbuf, 2 blocks/CU, 512 thr =
// 8 waves of 32x64, counted-vmcnt barriers. Four structurally different
// schedules (R0/R9/R15/R16) all measure 55-56us with MfmaUtil pinned at
// 24% -- the gemm's limiter is invariant to schedule/occupancy/barriers;
// this round's variable is prep.
__global__ __launch_bounds__(512, 4) void gemm_i8(
    const char* __restrict__ A,     // xq  M x K int8
    const char* __restrict__ B,     // w8  N x K int8
    const float* __restrict__ s_w,  // NG x OUT_F
    const float* __restrict__ sxr,  // M
    const float* __restrict__ bias,
    float* __restrict__ C) {
  __shared__ char smem[2][32768];           // per buf: A 16384 | B 16384 bytes
  __shared__ unsigned short sws[NG * 128];  // s_w for this block's 128 cols, bf16

  const int tid  = threadIdx.x;
  const int wave = tid >> 6;
  const int lane = tid & 63;
  const int bm = blockIdx.y << 7;
  const int bn = blockIdx.x << 7;
  const int wm = (wave >> 1) << 5;   // 4 wave-rows of 32
  const int wn = (wave & 1) << 6;    // 2 wave-cols of 64
  const int lrow = lane & 15;
  const int quad = lane >> 4;

  // stage s_w block into LDS as bf16 (keeps the K-loop free of global loads)
#pragma unroll
  for (int u = 0; u < 8; ++u) {
    int idx = u * 512 + tid;               // [g][c], c = local col
    int g = idx >> 7, c = idx & 127;
    __hip_bfloat16 h = __float2bfloat16(s_w[(size_t)g * OUT_F + bn + c]);
    sws[idx] = *(unsigned short*)&h;
  }

  f32x4 accf[2][4] = {};

  // Staging: per buf 2048 chunks of 16B. Round r = h*8+wave (h=0..3) covers
  // chunks c = r*64 + lane. c<1024 -> A (row=c>>3), else B. kc = (c&7)^(row&7).
  const char* gp[4];
  int lofs[4];
#pragma unroll
  for (int h = 0; h < 4; ++h) {
    int c0 = (h * 8 + wave) * 64;
    int c  = c0 + lane;
    if (c < 1024) {
      int row = c >> 3;
      int kc  = (c & 7) ^ (row & 7);
      gp[h]   = A + (size_t)(bm + row) * IN_F + kc * 16;
      lofs[h] = c0 * 16;
    } else {
      int cb  = c - 1024;
      int row = cb >> 3;
      int kc  = (cb & 7) ^ (row & 7);
      gp[h]   = B + (size_t)(bn + row) * IN_F + kc * 16;
      lofs[h] = 16384 + (c0 - 1024) * 16;
    }
  }

  auto stage = [&](int p, int kn) {
#pragma unroll
    for (int h = 0; h < 4; ++h)
      async16(gp[h] + kn, &smem[p][lofs[h]]);
  };

  auto compute = [&](int p, int g) {
    const char* bufA = smem[p];
    const char* bufB = smem[p] + 16384;
    v4i acci[2][4] = {};
#pragma unroll
    for (int s = 0; s < 2; ++s) {
      v4i af[2], bf[4];
#pragma unroll
      for (int i = 0; i < 2; ++i) {
        int row = wm + i * 16 + lrow;
        af[i] = *(const v4i*)&bufA[row * 128 + (((s << 2) + quad) ^ (row & 7)) * 16];
      }
#pragma unroll
      for (int j = 0; j < 4; ++j) {
        int row = wn + j * 16 + lrow;
        bf[j] = *(const v4i*)&bufB[row * 128 + (((s << 2) + quad) ^ (row & 7)) * 16];
      }
#pragma unroll
      for (int i = 0; i < 2; ++i)
#pragma unroll
        for (int j = 0; j < 4; ++j)
          acci[i][j] = __builtin_amdgcn_mfma_i32_16x16x64_i8(af[i], bf[j], acci[i][j], 0, 0, 0);
    }
    // per-group rescale (exact int32 -> f32, scaled by s_w[g, col])
    float swv[4];
#pragma unroll
    for (int j = 0; j < 4; ++j) {
      unsigned int u = sws[g * 128 + wn + j * 16 + lrow];
      swv[j] = __uint_as_float(u << 16);
    }
#pragma unroll
    for (int i = 0; i < 2; ++i)
#pragma unroll
      for (int j = 0; j < 4; ++j)
#pragma unroll
        for (int r = 0; r < 4; ++r)
          accf[i][j][r] += swv[j] * (float)acci[i][j][r];
  };

  // prologue: stage tiles 0 and 1 (4 DMAs each; queue = 8). vmcnt(4)
  // retires exactly tile 0's DMAs; tile 1's stay in flight across the
  // barrier with a full compute phase to land. lgkmcnt(0) publishes sws.
  stage(0, 0);
  stage(1, 128);
  asm volatile("s_waitcnt vmcnt(4) lgkmcnt(0)" ::: "memory");
  __builtin_amdgcn_s_barrier();
  asm volatile("" ::: "memory");

  for (int k0 = 0; k0 < IN_F; k0 += 256) {
    compute(0, k0 >> 7);                       // read buf0 (tile e)
    asm volatile("s_waitcnt lgkmcnt(0)" ::: "memory");
    __builtin_amdgcn_s_barrier();              // WAR: all waves done with buf0
    asm volatile("" ::: "memory");
    if (k0 + 256 < IN_F) {
      stage(0, k0 + 256);                      // tile e+2 -> buf0
      asm volatile("s_waitcnt vmcnt(4)" ::: "memory");  // retire tile e+1 DMAs
    } else {
      asm volatile("s_waitcnt vmcnt(0)" ::: "memory");  // tail: drain tile 31
    }
    __builtin_amdgcn_s_barrier();              // publish buf1
    asm volatile("" ::: "memory");
    compute(1, (k0 >> 7) + 1);                 // read buf1 (tile e+1)
    if (k0 + 256 < IN_F) {
      asm volatile("s_waitcnt lgkmcnt(0)" ::: "memory");
      __builtin_amdgcn_s_barrier();            // WAR: all waves done with buf1
      asm volatile("" ::: "memory");
      stage(1, k0 + 384);                      // tile e+3 -> buf1
      asm volatile("s_waitcnt vmcnt(4)" ::: "memory");  // retire tile e+2 DMAs
      __builtin_amdgcn_s_barrier();            // publish buf0
      asm volatile("" ::: "memory");
    }
  }

  // Epilogue: C/D layout col=lane&15, row=quad*4+reg (dtype-independent,
  // m89/m121-128). Apply per-row x-scale + bias.
#pragma unroll
  for (int i = 0; i < 2; ++i) {
    int r0 = bm + wm + i * 16 + quad * 4;
    float sxv[4];
#pragma unroll
    for (int r = 0; r < 4; ++r) sxv[r] = sxr[r0 + r];  // quad-broadcast loads
#pragma unroll
    for (int j = 0; j < 4; ++j) {
      int col = bn + wn + j * 16 + lrow;
      float bv = bias[col];
#pragma unroll
      for (int r = 0; r < 4; ++r)
        C[(size_t)(r0 + r) * OUT_F + col] = sxv[r] * accf[i][j][r] + bv;
    }
  }
}

// Correct-but-slow fp32 fallback if workspace is too small.
__global__ void naive_fallback(const float* __restrict__ x, const int* __restrict__ w_q,
                               const float* __restrict__ s_w, const void* __restrict__ perm_raw,
                               const float* __restrict__ bias, float* __restrict__ out) {
  int t = blockIdx.x * blockDim.x + threadIdx.x;
  int m = t >> 12;
  int o = t & 4095;
  const int f = g_perm_is64;
  const long long* p64 = (const long long*)perm_raw;
  const int*       p32 = (const int*)perm_raw;
  const float* xr = x + (size_t)m * IN_F;
  const int*   wr = w_q + (size_t)o * IN_F;
  float acc = 0.f;
  for (int g = 0; g < NG; ++g) {
    float part = 0.f;
    for (int k = 0; k < GRP; ++k) {
      int j = g * GRP + k;
      int pj = f ? (int)p64[j] : p32[j];
      part += xr[pj] * (float)wr[j];
    }
    acc += part * s_w[(size_t)g * OUT_F + o];
  }
  out[t] = acc + bias[o];
}

extern "C" void kernel_launch(void* const* d_in, const int* in_sizes, int n_in,
                              void* d_out, int out_size, void* d_ws, size_t ws_size,
                              hipStream_t stream) {
  const float* x    = (const float*)d_in[0];
  const int*   w_q  = (const int*)d_in[1];
  const float* s_w  = (const float*)d_in[2];
  const void*  perm = d_in[3];   // int64 or int32 -- detected on device
  const float* bias = (const float*)d_in[4];
  float* out = (float*)d_out;

  const size_t xq_bytes = (size_t)M_ROWS * IN_F;            // 8 MiB int8
  const size_t w8_bytes = (size_t)OUT_F * IN_F;             // 16 MiB int8
  const size_t sx_bytes = (size_t)M_ROWS * sizeof(float);   // 8 KiB
  const size_t need = xq_bytes + w8_bytes + sx_bytes;

  if (ws_size < need) {
    decode_flag<<<1, 64, 0, stream>>>(perm);
    naive_fallback<<<(M_ROWS * OUT_F) / 256, 256, 0, stream>>>(x, w_q, s_w, perm, bias, out);
    return;
  }

  char*  xq  = (char*)d_ws;
  char*  w8  = (char*)d_ws + xq_bytes;
  float* sxr = (float*)((char*)d_ws + xq_bytes + w8_bytes);

  prep<<<M_ROWS + OUT_F, 256, 0, stream>>>(x, w_q, perm, xq, w8, sxr);

  dim3 grid(OUT_F / 128, M_ROWS / 128);  // 32 x 16 = 512 blocks, 2/CU
  gemm_i8<<<grid, 512, 0, stream>>>(xq, w8, s_w, sxr, bias, out);
}